// Round 14
// baseline (341.108 us; speedup 1.0000x reference)
//
#include <hip/hip_runtime.h>
#include <math.h>

#define BB 2
#define NN 2048
#define DD 1024
#define KA 2048             /* augmented K/N dim */
#define HH 16
#define HD 64
#define MM (BB*NN)          /* 4096 */
#define SCALE 0.125f
#define NT (KA/32)

typedef __attribute__((ext_vector_type(8))) short bf16x8;
typedef __attribute__((ext_vector_type(4))) short bf16x4;
typedef __attribute__((ext_vector_type(4))) float f32x4;

#define MFMA(a,b,c) __builtin_amdgcn_mfma_f32_16x16x32_bf16(a,b,c,0,0,0)

__device__ __forceinline__ unsigned short f2bf(float x) {
    union { float f; unsigned u; } v; v.f = x;
    unsigned r = v.u + 0x7FFFu + ((v.u >> 16) & 1u);
    return (unsigned short)(r >> 16);
}

// async global->LDS, 16B per lane (wave-uniform LDS base + lane*16)
__device__ __forceinline__ void async16(void* l, const void* g) {
    __builtin_amdgcn_global_load_lds(
        (const __attribute__((address_space(1))) unsigned int*)g,
        (__attribute__((address_space(3))) unsigned int*)l, 16, 0, 0);
}

__device__ __forceinline__ bf16x8 ld8s(const short* p) {
    bf16x4 lo = *(const bf16x4*)p;
    bf16x4 hi = *(const bf16x4*)(p + 4);
    bf16x8 r;
    r[0]=lo[0]; r[1]=lo[1]; r[2]=lo[2]; r[3]=lo[3];
    r[4]=hi[0]; r[5]=hi[1]; r[6]=hi[2]; r[7]=hi[3];
    return r;
}
__device__ __forceinline__ void st8s(short* p, bf16x8 v) {
    bf16x4 lo, hi;
    lo[0]=v[0]; lo[1]=v[1]; lo[2]=v[2]; lo[3]=v[3];
    hi[0]=v[4]; hi[1]=v[5]; hi[2]=v[6]; hi[3]=v[7];
    *(bf16x4*)p = lo;
    *(bf16x4*)(p + 4) = hi;
}

// ---------------------------------------------------------------------------
// Per-batch mask prefix scan -> compact index list + count. grid BB, 256 thr.
// ---------------------------------------------------------------------------
__global__ __launch_bounds__(256) void mask_scan(const int* __restrict__ mask,
                                                 int* __restrict__ idxArr,
                                                 int* __restrict__ cntArr)
{
    const int b = blockIdx.x, t = threadIdx.x;
    __shared__ int part[256];
    int m[8]; int c = 0;
#pragma unroll
    for (int j = 0; j < 8; j++) { m[j] = mask[b*NN + t*8 + j]; c += (m[j] != 0); }
    part[t] = c; __syncthreads();
    for (int off = 1; off < 256; off <<= 1) {
        int v = (t >= off) ? part[t - off] : 0;
        __syncthreads();
        part[t] += v;
        __syncthreads();
    }
    int base = part[t] - c;
    int total = part[255];
#pragma unroll
    for (int j = 0; j < 8; j++) if (m[j]) idxArr[b*NN + base++] = t*8 + j;
    for (int p = total + t; p < NN; p += 256) idxArr[b*NN + p] = 0;
    if (t == 0) cntArr[b] = total;
}

// ---------------------------------------------------------------------------
// cvt + augmented build (unchanged).
// ---------------------------------------------------------------------------
__global__ __launch_bounds__(256) void cvt_aug(
    const float* __restrict__ Zr, const float* __restrict__ Zi,
    const float* __restrict__ wqr, const float* __restrict__ wqi,
    const float* __restrict__ wkr, const float* __restrict__ wki,
    const float* __restrict__ wvr, const float* __restrict__ wvi,
    const float* __restrict__ wor, const float* __restrict__ woi,
    unsigned short* __restrict__ Zaug,
    unsigned short* __restrict__ Wqa, unsigned short* __restrict__ Wka,
    unsigned short* __restrict__ Wva, unsigned short* __restrict__ Woa)
{
    const int bid = blockIdx.x, t = threadIdx.x;
    const int col = t * 8;
    const float* src;
    float sgn = 1.0f;
    unsigned short* dst;

    if (bid < 4096) {
        const int m = bid;
        src = (col < 1024) ? (Zr + (size_t)m*1024 + col) : (Zi + (size_t)m*1024 + col - 1024);
        dst = Zaug + (size_t)m * KA + col;
    } else {
        const int w = (bid - 4096) >> 11;
        const int r = (bid - 4096) & 2047;
        const int o = r & 1023;
        const float *wr_, *wi_;
        unsigned short* wa;
        switch (w) {
            case 0: wr_ = wqr; wi_ = wqi; wa = Wqa; break;
            case 1: wr_ = wkr; wi_ = wki; wa = Wka; break;
            case 2: wr_ = wvr; wi_ = wvi; wa = Wva; break;
            default: wr_ = wor; wi_ = woi; wa = Woa; break;
        }
        const bool imagrow = (r >= 1024);
        if (!imagrow) {
            if (col < 1024) { src = wr_ + (size_t)o*1024 + col; sgn = 1.0f; }
            else            { src = wi_ + (size_t)o*1024 + col - 1024; sgn = -1.0f; }
        } else {
            const float s = (w == 1) ? -1.0f : 1.0f;
            if (col < 1024) { src = wi_ + (size_t)o*1024 + col; sgn = s; }
            else            { src = wr_ + (size_t)o*1024 + col - 1024; sgn = s; }
        }
        dst = wa + (size_t)r * KA + col;
    }

    float4 a = *(const float4*)src;
    float4 b4 = *(const float4*)(src + 4);
    bf16x8 o8;
    o8[0]=(short)f2bf(sgn*a.x); o8[1]=(short)f2bf(sgn*a.y);
    o8[2]=(short)f2bf(sgn*a.z); o8[3]=(short)f2bf(sgn*a.w);
    o8[4]=(short)f2bf(sgn*b4.x); o8[5]=(short)f2bf(sgn*b4.y);
    o8[6]=(short)f2bf(sgn*b4.z); o8[7]=(short)f2bf(sgn*b4.w);
    *(bf16x8*)dst = o8;
}

// ---------------------------------------------------------------------------
// FUSED Q/K/V augmented projection. Block tile 256x128, per-wave 128x64
// (8x4 fragment grid) to cut LDS bytes/MFMA 1.36x. BK=64 single-buffer
// staging (round-10-proven structure), T2 swizzle chunk^(row&7).
// grid (48, 16): gx<16 Q tiles (256 rows); [16,32) K; [32,48) V.
// ---------------------------------------------------------------------------
__global__ __launch_bounds__(256) void proj_all(
    const unsigned short* __restrict__ Zaug,
    const unsigned short* __restrict__ Wqa, const unsigned short* __restrict__ Wka,
    const unsigned short* __restrict__ Wva,
    const float* __restrict__ bqr, const float* __restrict__ bqi,
    const float* __restrict__ bkr, const float* __restrict__ bki,
    const float* __restrict__ bvr, const float* __restrict__ bvi,
    const int* __restrict__ idxArr, const int* __restrict__ cntArr,
    unsigned short* __restrict__ Qr, unsigned short* __restrict__ Qi,
    unsigned short* __restrict__ Krc, unsigned short* __restrict__ nKic,
    unsigned short* __restrict__ Vtr, unsigned short* __restrict__ Vti)
{
    const int gx = blockIdx.x;
    int slice, b = 0, m0c;
    const unsigned short* wsel;
    const float *br, *bi;
    if (gx < 16) {
        slice = 0; m0c = gx * 256;
        wsel = Wqa; br = bqr; bi = bqi;
    } else if (gx < 32) {
        slice = 1; int t = gx - 16; b = t >> 3; m0c = (t & 7) * 256;
        wsel = Wka; br = bkr; bi = bki;
    } else {
        slice = 2; int t = gx - 32; b = t >> 3; m0c = (t & 7) * 256;
        wsel = Wva; br = bvr; bi = bvi;
    }
    if (slice != 0) {
        const int cnt = cntArr[b];
        if (m0c >= ((cnt + 63) & ~63)) return;
    }

    __shared__ __align__(16) short S[24576];   // A 256x64 (32KB) + B 128x64 (16KB)
    __shared__ int idx_s[256];

    const int tid = threadIdx.x;
    const int lane = tid & 63, wave = tid >> 6;
    const int lr = lane & 15, lg = lane >> 4;
    const int wrow = (wave >> 1) * 128, wcol = (wave & 1) * 64;
    const int o0 = blockIdx.y * 128;

    idx_s[tid] = (slice == 0) ? (m0c + tid) : (b*NN + idxArr[b*NN + m0c + tid]);
    __syncthreads();

    const int rsub8 = lane >> 3;                         // row&7 in every slot
    const int colo8 = (((lane & 7) ^ rsub8) * 8);        // inverse-swizzled source

    const unsigned short* gp[12];
    int lpo[12];
#pragma unroll
    for (int i = 0; i < 12; i++) {
        const int s = i * 4 + wave;       // 0..47
        if (s < 32) {                     // A: 256 rows, 32 slots
            const int row = s * 8 + rsub8;
            gp[i] = Zaug + (size_t)idx_s[row] * KA + colo8;
            lpo[i] = s * 1024 + lane * 16;
        } else {                          // B: 128 rows, 16 slots
            const int row = (s - 32) * 8 + rsub8;
            gp[i] = wsel + (size_t)(o0 + row) * KA + colo8;
            lpo[i] = 32768 + (s - 32) * 1024 + lane * 16;
        }
    }

    f32x4 acc[8][4];
#pragma unroll
    for (int m = 0; m < 8; m++)
#pragma unroll
        for (int n = 0; n < 4; n++) acc[m][n] = (f32x4){0.f,0.f,0.f,0.f};

    const short (*Sa)[64] = (const short (*)[64])S;
    const short (*Sb)[64] = (const short (*)[64])(S + 16384);

    for (int k0 = 0; k0 < KA; k0 += 64) {
        __syncthreads();
#pragma unroll
        for (int i = 0; i < 12; i++) {
            async16((char*)S + lpo[i], gp[i]);
            gp[i] += 64;
        }
        __syncthreads();

#pragma unroll
        for (int half = 0; half < 2; half++) {
            const int kb = ((half * 4 + lg) ^ (lr & 7)) * 8;
            bf16x8 af[8], bw[4];
#pragma unroll
            for (int m = 0; m < 8; m++) af[m] = *(const bf16x8*)&Sa[wrow + m*16 + lr][kb];
#pragma unroll
            for (int n = 0; n < 4; n++) bw[n] = *(const bf16x8*)&Sb[wcol + n*16 + lr][kb];
#pragma unroll
            for (int m = 0; m < 8; m++)
#pragma unroll
                for (int n = 0; n < 4; n++) acc[m][n] = MFMA(af[m], bw[n], acc[m][n]);
        }
    }

#pragma unroll
    for (int mi = 0; mi < 8; mi++)
#pragma unroll
        for (int nj = 0; nj < 4; nj++) {
            const int o = o0 + wcol + nj*16 + lr;     // 0..2047
            const int half = o >> 10;                 // 0 real, 1 imag
            const int oc = o & 1023;
            const int h = oc >> 6, hd = oc & 63;
            const float bias = half ? ((slice == 1) ? -bi[oc] : bi[oc]) : br[oc];
            if (slice == 2) {        // V: transposed store [b,h,hd,jc]
                bf16x4 p4;
#pragma unroll
                for (int reg = 0; reg < 4; reg++)
                    p4[reg] = (short)f2bf(acc[mi][nj][reg] + bias);
                const int jc = m0c + wrow + mi*16 + lg*4;
                size_t base = ((size_t)((b*HH + h)*HD + hd)) * NN + jc;
                if (half) *(bf16x4*)&Vti[base] = p4;
                else      *(bf16x4*)&Vtr[base] = p4;
            } else if (slice == 1) { // K: head-major; imag path already negated
                unsigned short* dst = half ? nKic : Krc;
#pragma unroll
                for (int reg = 0; reg < 4; reg++) {
                    const int jc = m0c + wrow + mi*16 + lg*4 + reg;
                    dst[((size_t)((b*HH + h)*NN + jc)) * HD + hd] =
                        f2bf(acc[mi][nj][reg] + bias);
                }
            } else {                 // Q: head-major, pre-scaled
                unsigned short* dst = half ? Qi : Qr;
#pragma unroll
                for (int reg = 0; reg < 4; reg++) {
                    const int m = m0c + wrow + mi*16 + lg*4 + reg;
                    const int b2 = m >> 11, n = m & (NN - 1);
                    dst[((size_t)((b2*HH + h)*NN + n)) * HD + hd] =
                        f2bf((acc[mi][nj][reg] + bias) * SCALE);
                }
            }
        }
}

// ---------------------------------------------------------------------------
// MFMA flash attention over compacted keys. grid (NN/128, HH, BB), block 256
// (4 waves x 32 q-rows). Output -> Aaug[4096][2048] (real | imag halves).
// (Unchanged passing version.)
// ---------------------------------------------------------------------------
#define LDP 72
__global__ __launch_bounds__(256) void attn_mfma(
    const unsigned short* __restrict__ Qr, const unsigned short* __restrict__ Qi,
    const unsigned short* __restrict__ Krc, const unsigned short* __restrict__ nKic,
    const unsigned short* __restrict__ Vtc, const unsigned short* __restrict__ Vtic,
    const int* __restrict__ cntArr,
    unsigned short* __restrict__ Aaug)
{
    __shared__ short Kr_s[64][LDP], Ki_s[64][LDP], Vr_s[64][LDP], Vi_s[64][LDP];
    __shared__ short P_s[4][32][LDP];

    const int tid = threadIdx.x;
    const int lane = tid & 63, wave = tid >> 6;
    const int lr = lane & 15, lg = lane >> 4;
    const int h = blockIdx.y, b = blockIdx.z;
    const int n0 = blockIdx.x * 128 + wave * 32;
    const size_t qb = ((size_t)(b*HH + h)) * NN * HD;
    const int cnt = cntArr[b];
    const int ct = (cnt + 63) & ~63;

    bf16x8 qr[2][2], qi[2][2];
#pragma unroll
    for (int mf = 0; mf < 2; mf++)
#pragma unroll
        for (int kf = 0; kf < 2; kf++) {
            qr[mf][kf] = *(const bf16x8*)&Qr[qb + (size_t)(n0 + mf*16 + lr) * HD + kf*32 + lg*8];
            qi[mf][kf] = *(const bf16x8*)&Qi[qb + (size_t)(n0 + mf*16 + lr) * HD + kf*32 + lg*8];
        }

    f32x4 o_r[2][4], o_i[2][4];
#pragma unroll
    for (int mf = 0; mf < 2; mf++)
#pragma unroll
        for (int nf = 0; nf < 4; nf++) {
            o_r[mf][nf] = (f32x4){0.f,0.f,0.f,0.f};
            o_i[mf][nf] = (f32x4){0.f,0.f,0.f,0.f};
        }
    float m_run[2][4], l_run[2][4];
#pragma unroll
    for (int mf = 0; mf < 2; mf++)
#pragma unroll
        for (int r = 0; r < 4; r++) { m_run[mf][r] = -3.0e38f; l_run[mf][r] = 0.0f; }

    for (int t0 = 0; t0 < ct; t0 += 64) {
        __syncthreads();
        for (int c = tid; c < 512; c += 256) {
            int row = c >> 3, ch = (c & 7) * 8;
            st8s(&Kr_s[row][ch], *(const bf16x8*)&Krc [qb + (size_t)(t0 + row) * HD + ch]);
            st8s(&Ki_s[row][ch], *(const bf16x8*)&nKic[qb + (size_t)(t0 + row) * HD + ch]);
            st8s(&Vr_s[row][ch], *(const bf16x8*)&Vtc [qb + (size_t)row * NN + t0 + ch]);
            st8s(&Vi_s[row][ch], *(const bf16x8*)&Vtic[qb + (size_t)row * NN + t0 + ch]);
        }
        __syncthreads();

        // ---- scores ----
        f32x4 sacc[2][4];
#pragma unroll
        for (int nf = 0; nf < 4; nf++) {
            bf16x8 k0f = ld8s(&Kr_s[nf*16 + lr][lg*8]);
            bf16x8 k1f = ld8s(&Kr_s[nf*16 + lr][32 + lg*8]);
            bf16x8 i0f = ld8s(&Ki_s[nf*16 + lr][lg*8]);
            bf16x8 i1f = ld8s(&Ki_s[nf*16 + lr][32 + lg*8]);
#pragma unroll
            for (int mf = 0; mf < 2; mf++) {
                f32x4 a = (f32x4){0.f,0.f,0.f,0.f};
                a = MFMA(qr[mf][0], k0f, a);
                a = MFMA(qr[mf][1], k1f, a);
                a = MFMA(qi[mf][0], i0f, a);
                a = MFMA(qi[mf][1], i1f, a);
                sacc[mf][nf] = a;
            }
        }

        // tail masking (only in last tile)
        if (t0 + 64 > cnt) {
#pragma unroll
            for (int nf = 0; nf < 4; nf++) {
                if (t0 + nf*16 + lr >= cnt) {
#pragma unroll
                    for (int mf = 0; mf < 2; mf++)
#pragma unroll
                        for (int r = 0; r < 4; r++) sacc[mf][nf][r] = -1e9f;
                }
            }
        }

        // ---- online softmax (rows = lg*4+r, cols = nf*16+lr) ----
#pragma unroll
        for (int mf = 0; mf < 2; mf++) {
            float fac[4];
#pragma unroll
            for (int r = 0; r < 4; r++) {
                float v = fmaxf(fmaxf(sacc[mf][0][r], sacc[mf][1][r]),
                                fmaxf(sacc[mf][2][r], sacc[mf][3][r]));
                v = fmaxf(v, __shfl_xor(v, 1, 64));
                v = fmaxf(v, __shfl_xor(v, 2, 64));
                v = fmaxf(v, __shfl_xor(v, 4, 64));
                v = fmaxf(v, __shfl_xor(v, 8, 64));
                float mn = fmaxf(m_run[mf][r], v);
                fac[r] = __expf(m_run[mf][r] - mn);
                m_run[mf][r] = mn;
            }
            float psum[4] = {0.f, 0.f, 0.f, 0.f};
#pragma unroll
            for (int nf = 0; nf < 4; nf++)
#pragma unroll
                for (int r = 0; r < 4; r++) {
                    float p = __expf(sacc[mf][nf][r] - m_run[mf][r]);
                    psum[r] += p;
                    P_s[wave][mf*16 + lg*4 + r][nf*16 + lr] = (short)f2bf(p);
                }
#pragma unroll
            for (int r = 0; r < 4; r++) {
                float ps = psum[r];
                ps += __shfl_xor(ps, 1, 64);
                ps += __shfl_xor(ps, 2, 64);
                ps += __shfl_xor(ps, 4, 64);
                ps += __shfl_xor(ps, 8, 64);
                l_run[mf][r] = l_run[mf][r] * fac[r] + ps;
            }
#pragma unroll
            for (int nf = 0; nf < 4; nf++)
#pragma unroll
                for (int r = 0; r < 4; r++) {
                    o_r[mf][nf][r] *= fac[r];
                    o_i[mf][nf][r] *= fac[r];
                }
        }
        __syncthreads();   // P_s visibility

        // ---- PV ----
        bf16x8 pa[2][2];
#pragma unroll
        for (int mf = 0; mf < 2; mf++) {
            pa[mf][0] = ld8s(&P_s[wave][mf*16 + lr][lg*8]);
            pa[mf][1] = ld8s(&P_s[wave][mf*16 + lr][32 + lg*8]);
        }
#pragma unroll
        for (int nf = 0; nf < 4; nf++) {
            bf16x8 v0 = ld8s(&Vr_s[nf*16 + lr][lg*8]);
            bf16x8 v1 = ld8s(&Vr_s[nf*16 + lr][32 + lg*8]);
            bf16x8 w0 = ld8s(&Vi_s[nf*16 + lr][lg*8]);
            bf16x8 w1 = ld8s(&Vi_s[nf*16 + lr][32 + lg*8]);
#pragma unroll
            for (int mf = 0; mf < 2; mf++) {
                o_r[mf][nf] = MFMA(pa[mf][0], v0, o_r[mf][nf]);
                o_r[mf][nf] = MFMA(pa[mf][1], v1, o_r[mf][nf]);
                o_i[mf][nf] = MFMA(pa[mf][0], w0, o_i[mf][nf]);
                o_i[mf][nf] = MFMA(pa[mf][1], w1, o_i[mf][nf]);
            }
        }
    }

#pragma unroll
    for (int mf = 0; mf < 2; mf++) {
        float invl[4];
#pragma unroll
        for (int r = 0; r < 4; r++) invl[r] = 1.0f / l_run[mf][r];
#pragma unroll
        for (int nf = 0; nf < 4; nf++)
#pragma unroll
            for (int r = 0; r < 4; r++) {
                int row = n0 + mf*16 + lg*4 + r;
                int col = h*HD + nf*16 + lr;
                size_t o = ((size_t)(b*NN + row)) * KA + col;
                Aaug[o]        = f2bf(o_r[mf][nf][r] * invl[r]);
                Aaug[o + 1024] = f2bf(o_i[mf][nf][r] * invl[r]);
            }
    }
}

// ---------------------------------------------------------------------------
// Final augmented GEMM + bias + residual: BK=32 3-buffer counted-vmcnt
// pipeline (round-13 passing version, unchanged). grid (32, 16), block 256.
// ---------------------------------------------------------------------------
__global__ __launch_bounds__(256) void final_mfma(
    const unsigned short* __restrict__ Aaug, const unsigned short* __restrict__ Woa,
    const float* __restrict__ bor, const float* __restrict__ boi,
    const float* __restrict__ Zr, const float* __restrict__ Zi,
    float* __restrict__ out)
{
    __shared__ __align__(16) short S[3][2][128][32];

    const int tid = threadIdx.x;
    const int lane = tid & 63, wave = tid >> 6;
    const int lr = lane & 15, lg = lane >> 4;
    const int wrow = (wave >> 1) * 64, wcol = (wave & 1) * 64;
    const int m0 = blockIdx.x * 128, o0 = blockIdx.y * 128;

    const int rsub = lane >> 2;
    const int csrc = (((lane & 3) ^ ((lane >> 3) & 3)) * 8);

    const unsigned short* gp[4];
    int lpo[4];
#pragma unroll
    for (int i = 0; i < 4; i++) {
        const int s = i * 4 + wave;
        if (s < 8) {
            const int row = s * 16 + rsub;
            gp[i] = Aaug + (size_t)(m0 + row) * KA + csrc;
            lpo[i] = s * 1024 + lane * 16;
        } else {
            const int row = (s - 8) * 16 + rsub;
            gp[i] = Woa + (size_t)(o0 + row) * KA + csrc;
            lpo[i] = 8192 + (s - 8) * 1024 + lane * 16;
        }
    }

    f32x4 acc[4][4];
#pragma unroll
    for (int m = 0; m < 4; m++)
#pragma unroll
        for (int n = 0; n < 4; n++) acc[m][n] = (f32x4){0.f,0.f,0.f,0.f};

#pragma unroll
    for (int i = 0; i < 4; i++) { async16((char*)S + lpo[i], gp[i]); gp[i] += 32; }
#pragma unroll
    for (int i = 0; i < 4; i++) { async16((char*)S + 16384 + lpo[i], gp[i]); gp[i] += 32; }

    const int kb = ((lg ^ ((lr >> 1) & 3)) * 8);

    int cur = 0, stg = 2;
    for (int t = 0; t < NT - 1; t++) {
        asm volatile("s_waitcnt vmcnt(4)" ::: "memory");
        __builtin_amdgcn_s_barrier();
        __builtin_amdgcn_sched_barrier(0);

        if (t + 2 < NT) {
            char* nb = (char*)S + stg * 16384;
#pragma unroll
            for (int i = 0; i < 4; i++) { async16(nb + lpo[i], gp[i]); gp[i] += 32; }
        }

        const short (*Sa)[32] = (const short (*)[32])((const char*)S + cur * 16384);
        const short (*Sb)[32] = Sa + 128;
        bf16x8 af[4], bw[4];
#pragma unroll
        for (int m = 0; m < 4; m++) af[m] = *(const bf16x8*)&Sa[wrow + m*16 + lr][kb];
#pragma unroll
        for (int n = 0; n < 4; n++) bw[n] = *(const bf16x8*)&Sb[wcol + n*16 + lr][kb];
#pragma unroll
        for (int m = 0; m < 4; m++)
#pragma unroll
            for (int n = 0; n < 4; n++) acc[m][n] = MFMA(af[m], bw[n], acc[m][n]);

        cur = (cur == 2) ? 0 : cur + 1;
        stg = (stg == 2) ? 0 : stg + 1;
    }
    asm volatile("s_waitcnt vmcnt(0)" ::: "memory");
    __builtin_amdgcn_s_barrier();
    __builtin_amdgcn_sched_barrier(0);
    {
        const short (*Sa)[32] = (const short (*)[32])((const char*)S + cur * 16384);
        const short (*Sb)[32] = Sa + 128;
        bf16x8 af[4], bw[4];
#pragma unroll
        for (int m = 0; m < 4; m++) af[m] = *(const bf16x8*)&Sa[wrow + m*16 + lr][kb];
#pragma unroll
        for (int n = 0; n < 4; n++) bw[n] = *(const bf16x8*)&Sb[wcol + n*16 + lr][kb];
#pragma unroll
        for (int m = 0; m < 4; m++)
#pragma unroll
            for (int n = 0; n < 4; n++) acc[m][n] = MFMA(af[m], bw[n], acc[m][n]);
    }

#pragma unroll
    for (int mi = 0; mi < 4; mi++)
#pragma unroll
        for (int nj = 0; nj < 4; nj++) {
            const int o = o0 + wcol + nj*16 + lr;
            const int half = o >> 10;
            const int oc = o & 1023;
            const float bias = half ? boi[oc] : bor[oc];
            const float* resid = half ? Zi : Zr;
            float* dst = out + (half ? (size_t)MM * DD : 0);
#pragma unroll
            for (int reg = 0; reg < 4; reg++) {
                const int m = m0 + wrow + mi*16 + lg*4 + reg;
                size_t zi = (size_t)m * DD + oc;
                dst[zi] = acc[mi][nj][reg] + bias + resid[zi];
            }
        }
}

// ---------------------------------------------------------------------------
extern "C" void kernel_launch(void* const* d_in, const int* in_sizes, int n_in,
                              void* d_out, int out_size, void* d_ws, size_t ws_size,
                              hipStream_t stream)
{
    const float* Zr  = (const float*)d_in[0];
    const float* Zi  = (const float*)d_in[1];
    const float* wqr = (const float*)d_in[2];
    const float* wqi = (const float*)d_in[3];
    const float* bqr = (const float*)d_in[4];
    const float* bqi = (const float*)d_in[5];
    const float* wkr = (const float*)d_in[6];
    const float* wki = (const float*)d_in[7];
    const float* bkr = (const float*)d_in[8];
    const float* bki = (const float*)d_in[9];
    const float* wvr = (const float*)d_in[10];
    const float* wvi = (const float*)d_in[11];
    const float* bvr = (const float*)d_in[12];
    const float* bvi = (const float*)d_in[13];
    const float* wor = (const float*)d_in[14];
    const float* woi = (const float*)d_in[15];
    const float* bor = (const float*)d_in[16];
    const float* boi = (const float*)d_in[17];
    const int*  mask = (const int*)d_in[18];

    unsigned short* w16 = (unsigned short*)d_ws;
    const size_t ZA = (size_t)MM * KA;      // 8M shorts (16 MB)
    const size_t WA = (size_t)KA * KA;      // 4M shorts (8 MB)
    const size_t HN = (size_t)MM * DD;      // 4M shorts
    unsigned short* Zaug = w16;
    unsigned short* Wqa  = Zaug + ZA;
    unsigned short* Wka  = Wqa + WA;
    unsigned short* Wva  = Wka + WA;
    unsigned short* Woa  = Wva + WA;
    unsigned short* Qr16 = Woa + WA;
    unsigned short* Qi16 = Qr16 + HN;
    unsigned short* Krc16 = Qi16 + HN;
    unsigned short* nKic16 = Krc16 + HN;
    unsigned short* Vtr16 = nKic16 + HN;
    unsigned short* Vti16 = Vtr16 + HN;
    unsigned short* Aaug = Vti16 + HN;
    int* idxArr = (int*)(Aaug + ZA);
    int* cntArr = idxArr + BB * NN;

    mask_scan<<<BB, 256, 0, stream>>>(mask, idxArr, cntArr);

    cvt_aug<<<12288, 256, 0, stream>>>(
        Zr, Zi, wqr, wqi, wkr, wki, wvr, wvi, wor, woi,
        Zaug, Wqa, Wka, Wva, Woa);

    proj_all<<<dim3(48, 16), 256, 0, stream>>>(
        Zaug, Wqa, Wka, Wva,
        bqr, bqi, bkr, bki, bvr, bvi, idxArr, cntArr,
        Qr16, Qi16, Krc16, nKic16, Vtr16, Vti16);

    attn_mfma<<<dim3(NN/128, HH, BB), 256, 0, stream>>>(
        Qr16, Qi16, Krc16, nKic16, Vtr16, Vti16, cntArr, Aaug);

    final_mfma<<<dim3(32, 16), 256, 0, stream>>>(
        Aaug, Woa, bor, boi, Zr, Zi, (float*)d_out);
}

// Round 15
// 263.271 us; speedup vs baseline: 1.2957x; 1.2957x over previous
//
#include <hip/hip_runtime.h>
#include <math.h>

#define BB 2
#define NN 2048
#define DD 1024
#define KA 2048             /* augmented K/N dim */
#define HH 16
#define HD 64
#define MM (BB*NN)          /* 4096 */
#define SCALE 0.125f
#define NT (KA/32)          /* 64 K-steps at BK=32 */

typedef __attribute__((ext_vector_type(8))) short bf16x8;
typedef __attribute__((ext_vector_type(4))) short bf16x4;
typedef __attribute__((ext_vector_type(4))) float f32x4;

#define MFMA(a,b,c) __builtin_amdgcn_mfma_f32_16x16x32_bf16(a,b,c,0,0,0)

__device__ __forceinline__ unsigned short f2bf(float x) {
    union { float f; unsigned u; } v; v.f = x;
    unsigned r = v.u + 0x7FFFu + ((v.u >> 16) & 1u);
    return (unsigned short)(r >> 16);
}

// async global->LDS, 16B per lane (wave-uniform LDS base + lane*16)
__device__ __forceinline__ void async16(void* l, const void* g) {
    __builtin_amdgcn_global_load_lds(
        (const __attribute__((address_space(1))) unsigned int*)g,
        (__attribute__((address_space(3))) unsigned int*)l, 16, 0, 0);
}

__device__ __forceinline__ bf16x8 ld8s(const short* p) {
    bf16x4 lo = *(const bf16x4*)p;
    bf16x4 hi = *(const bf16x4*)(p + 4);
    bf16x8 r;
    r[0]=lo[0]; r[1]=lo[1]; r[2]=lo[2]; r[3]=lo[3];
    r[4]=hi[0]; r[5]=hi[1]; r[6]=hi[2]; r[7]=hi[3];
    return r;
}
__device__ __forceinline__ void st8s(short* p, bf16x8 v) {
    bf16x4 lo, hi;
    lo[0]=v[0]; lo[1]=v[1]; lo[2]=v[2]; lo[3]=v[3];
    hi[0]=v[4]; hi[1]=v[5]; hi[2]=v[6]; hi[3]=v[7];
    *(bf16x4*)p = lo;
    *(bf16x4*)(p + 4) = hi;
}

// ---------------------------------------------------------------------------
// FUSED cvt + augmented build + mask scan.
// Blocks 0..12287: Zaug[4096][2048]=[Zr|Zi]; Waug per weight:
//   row o<1024: [Wr|-Wi]; row>=1024: s*[Wi|Wr] (s=-1 for K).
// Blocks 12288..12289: per-batch mask prefix scan -> idxArr/cntArr.
// ---------------------------------------------------------------------------
__global__ __launch_bounds__(256) void cvt_aug(
    const float* __restrict__ Zr, const float* __restrict__ Zi,
    const float* __restrict__ wqr, const float* __restrict__ wqi,
    const float* __restrict__ wkr, const float* __restrict__ wki,
    const float* __restrict__ wvr, const float* __restrict__ wvi,
    const float* __restrict__ wor, const float* __restrict__ woi,
    unsigned short* __restrict__ Zaug,
    unsigned short* __restrict__ Wqa, unsigned short* __restrict__ Wka,
    unsigned short* __restrict__ Wva, unsigned short* __restrict__ Woa,
    const int* __restrict__ mask,
    int* __restrict__ idxArr, int* __restrict__ cntArr)
{
    const int bid = blockIdx.x, t = threadIdx.x;

    if (bid >= 12288) {   // ---- mask scan path ----
        const int b = bid - 12288;
        __shared__ int part[256];
        int m[8]; int c = 0;
#pragma unroll
        for (int j = 0; j < 8; j++) { m[j] = mask[b*NN + t*8 + j]; c += (m[j] != 0); }
        part[t] = c; __syncthreads();
        for (int off = 1; off < 256; off <<= 1) {
            int v = (t >= off) ? part[t - off] : 0;
            __syncthreads();
            part[t] += v;
            __syncthreads();
        }
        int base = part[t] - c;
        int total = part[255];
#pragma unroll
        for (int j = 0; j < 8; j++) if (m[j]) idxArr[b*NN + base++] = t*8 + j;
        for (int p = total + t; p < NN; p += 256) idxArr[b*NN + p] = 0;
        if (t == 0) cntArr[b] = total;
        return;
    }

    const int col = t * 8;
    const float* src;
    float sgn = 1.0f;
    unsigned short* dst;

    if (bid < 4096) {
        const int m = bid;
        src = (col < 1024) ? (Zr + (size_t)m*1024 + col) : (Zi + (size_t)m*1024 + col - 1024);
        dst = Zaug + (size_t)m * KA + col;
    } else {
        const int w = (bid - 4096) >> 11;
        const int r = (bid - 4096) & 2047;
        const int o = r & 1023;
        const float *wr_, *wi_;
        unsigned short* wa;
        switch (w) {
            case 0: wr_ = wqr; wi_ = wqi; wa = Wqa; break;
            case 1: wr_ = wkr; wi_ = wki; wa = Wka; break;
            case 2: wr_ = wvr; wi_ = wvi; wa = Wva; break;
            default: wr_ = wor; wi_ = woi; wa = Woa; break;
        }
        const bool imagrow = (r >= 1024);
        if (!imagrow) {
            if (col < 1024) { src = wr_ + (size_t)o*1024 + col; sgn = 1.0f; }
            else            { src = wi_ + (size_t)o*1024 + col - 1024; sgn = -1.0f; }
        } else {
            const float s = (w == 1) ? -1.0f : 1.0f;
            if (col < 1024) { src = wi_ + (size_t)o*1024 + col; sgn = s; }
            else            { src = wr_ + (size_t)o*1024 + col - 1024; sgn = s; }
        }
        dst = wa + (size_t)r * KA + col;
    }

    float4 a = *(const float4*)src;
    float4 b4 = *(const float4*)(src + 4);
    bf16x8 o8;
    o8[0]=(short)f2bf(sgn*a.x); o8[1]=(short)f2bf(sgn*a.y);
    o8[2]=(short)f2bf(sgn*a.z); o8[3]=(short)f2bf(sgn*a.w);
    o8[4]=(short)f2bf(sgn*b4.x); o8[5]=(short)f2bf(sgn*b4.y);
    o8[6]=(short)f2bf(sgn*b4.z); o8[7]=(short)f2bf(sgn*b4.w);
    *(bf16x8*)dst = o8;
}

// ---------------------------------------------------------------------------
// FUSED Q/K/V augmented projection. BK=32, 3-buffer counted-vmcnt pipeline
// (round-13 passing version, unchanged). grid (96, 16), block 256.
// ---------------------------------------------------------------------------
__global__ __launch_bounds__(256) void proj_all(
    const unsigned short* __restrict__ Zaug,
    const unsigned short* __restrict__ Wqa, const unsigned short* __restrict__ Wka,
    const unsigned short* __restrict__ Wva,
    const float* __restrict__ bqr, const float* __restrict__ bqi,
    const float* __restrict__ bkr, const float* __restrict__ bki,
    const float* __restrict__ bvr, const float* __restrict__ bvi,
    const int* __restrict__ idxArr, const int* __restrict__ cntArr,
    unsigned short* __restrict__ Qr, unsigned short* __restrict__ Qi,
    unsigned short* __restrict__ Krc, unsigned short* __restrict__ nKic,
    unsigned short* __restrict__ Vtr, unsigned short* __restrict__ Vti)
{
    const int gx = blockIdx.x;
    int slice, b = 0, m0c;
    const unsigned short* wsel;
    const float *br, *bi;
    if (gx < 32) {
        slice = 0; m0c = gx * 128;
        wsel = Wqa; br = bqr; bi = bqi;
    } else if (gx < 64) {
        slice = 1; int t = gx - 32; b = t >> 4; m0c = (t & 15) * 128;
        wsel = Wka; br = bkr; bi = bki;
    } else {
        slice = 2; int t = gx - 64; b = t >> 4; m0c = (t & 15) * 128;
        wsel = Wva; br = bvr; bi = bvi;
    }
    if (slice != 0) {
        const int cnt = cntArr[b];
        if (m0c >= ((cnt + 63) & ~63)) return;
    }

    __shared__ __align__(16) short S[3][2][128][32];   // 3 bufs x (A,B) 16KB
    __shared__ int idx_s[128];

    const int tid = threadIdx.x;
    const int lane = tid & 63, wave = tid >> 6;
    const int lr = lane & 15, lg = lane >> 4;
    const int wrow = (wave >> 1) * 64, wcol = (wave & 1) * 64;
    const int o0 = blockIdx.y * 128;

    if (tid < 128)
        idx_s[tid] = (slice == 0) ? (m0c + tid) : (b*NN + idxArr[b*NN + m0c + tid]);
    __syncthreads();

    const int rsub = lane >> 2;
    const int csrc = (((lane & 3) ^ ((lane >> 3) & 3)) * 8);

    const unsigned short* gp[4];
    int lpo[4];
#pragma unroll
    for (int i = 0; i < 4; i++) {
        const int s = i * 4 + wave;       // 0..15
        if (s < 8) {
            const int row = s * 16 + rsub;
            gp[i] = Zaug + (size_t)idx_s[row] * KA + csrc;
            lpo[i] = s * 1024 + lane * 16;
        } else {
            const int row = (s - 8) * 16 + rsub;
            gp[i] = wsel + (size_t)(o0 + row) * KA + csrc;
            lpo[i] = 8192 + (s - 8) * 1024 + lane * 16;
        }
    }

    f32x4 acc[4][4];
#pragma unroll
    for (int m = 0; m < 4; m++)
#pragma unroll
        for (int n = 0; n < 4; n++) acc[m][n] = (f32x4){0.f,0.f,0.f,0.f};

    // prologue: stage T0 -> buf0, T1 -> buf1
#pragma unroll
    for (int i = 0; i < 4; i++) { async16((char*)S + lpo[i], gp[i]); gp[i] += 32; }
#pragma unroll
    for (int i = 0; i < 4; i++) { async16((char*)S + 16384 + lpo[i], gp[i]); gp[i] += 32; }

    const int kb = ((lg ^ ((lr >> 1) & 3)) * 8);       // swizzled read chunk

    int cur = 0, stg = 2;
    for (int t = 0; t < NT - 1; t++) {
        asm volatile("s_waitcnt vmcnt(4)" ::: "memory");
        __builtin_amdgcn_s_barrier();
        __builtin_amdgcn_sched_barrier(0);

        if (t + 2 < NT) {
            char* nb = (char*)S + stg * 16384;
#pragma unroll
            for (int i = 0; i < 4; i++) { async16(nb + lpo[i], gp[i]); gp[i] += 32; }
        }

        const short (*Sa)[32] = (const short (*)[32])((const char*)S + cur * 16384);
        const short (*Sb)[32] = Sa + 128;
        bf16x8 af[4], bw[4];
#pragma unroll
        for (int m = 0; m < 4; m++) af[m] = *(const bf16x8*)&Sa[wrow + m*16 + lr][kb];
#pragma unroll
        for (int n = 0; n < 4; n++) bw[n] = *(const bf16x8*)&Sb[wcol + n*16 + lr][kb];
#pragma unroll
        for (int m = 0; m < 4; m++)
#pragma unroll
            for (int n = 0; n < 4; n++) acc[m][n] = MFMA(af[m], bw[n], acc[m][n]);

        cur = (cur == 2) ? 0 : cur + 1;
        stg = (stg == 2) ? 0 : stg + 1;
    }
    // peeled last K-step: must fully drain
    asm volatile("s_waitcnt vmcnt(0)" ::: "memory");
    __builtin_amdgcn_s_barrier();
    __builtin_amdgcn_sched_barrier(0);
    {
        const short (*Sa)[32] = (const short (*)[32])((const char*)S + cur * 16384);
        const short (*Sb)[32] = Sa + 128;
        bf16x8 af[4], bw[4];
#pragma unroll
        for (int m = 0; m < 4; m++) af[m] = *(const bf16x8*)&Sa[wrow + m*16 + lr][kb];
#pragma unroll
        for (int n = 0; n < 4; n++) bw[n] = *(const bf16x8*)&Sb[wcol + n*16 + lr][kb];
#pragma unroll
        for (int m = 0; m < 4; m++)
#pragma unroll
            for (int n = 0; n < 4; n++) acc[m][n] = MFMA(af[m], bw[n], acc[m][n]);
    }

#pragma unroll
    for (int mi = 0; mi < 4; mi++)
#pragma unroll
        for (int nj = 0; nj < 4; nj++) {
            const int o = o0 + wcol + nj*16 + lr;     // 0..2047
            const int half = o >> 10;                 // 0 real, 1 imag
            const int oc = o & 1023;
            const int h = oc >> 6, hd = oc & 63;
            const float bias = half ? ((slice == 1) ? -bi[oc] : bi[oc]) : br[oc];
            if (slice == 2) {        // V: transposed store [b,h,hd,jc]
                bf16x4 p4;
#pragma unroll
                for (int reg = 0; reg < 4; reg++)
                    p4[reg] = (short)f2bf(acc[mi][nj][reg] + bias);
                const int jc = m0c + wrow + mi*16 + lg*4;
                size_t base = ((size_t)((b*HH + h)*HD + hd)) * NN + jc;
                if (half) *(bf16x4*)&Vti[base] = p4;
                else      *(bf16x4*)&Vtr[base] = p4;
            } else if (slice == 1) { // K: head-major; imag path already negated
                unsigned short* dst = half ? nKic : Krc;
#pragma unroll
                for (int reg = 0; reg < 4; reg++) {
                    const int jc = m0c + wrow + mi*16 + lg*4 + reg;
                    dst[((size_t)((b*HH + h)*NN + jc)) * HD + hd] =
                        f2bf(acc[mi][nj][reg] + bias);
                }
            } else {                 // Q: head-major, pre-scaled
                unsigned short* dst = half ? Qi : Qr;
#pragma unroll
                for (int reg = 0; reg < 4; reg++) {
                    const int m = m0c + wrow + mi*16 + lg*4 + reg;
                    const int b2 = m >> 11, n = m & (NN - 1);
                    dst[((size_t)((b2*HH + h)*NN + n)) * HD + hd] =
                        f2bf((acc[mi][nj][reg] + bias) * SCALE);
                }
            }
        }
}

// ---------------------------------------------------------------------------
// MFMA flash attention over compacted keys. grid (NN/128, HH, BB), block 256
// (4 waves x 32 q-rows). Output -> Aaug[4096][2048] (real | imag halves).
// (Unchanged passing version.)
// ---------------------------------------------------------------------------
#define LDP 72
__global__ __launch_bounds__(256) void attn_mfma(
    const unsigned short* __restrict__ Qr, const unsigned short* __restrict__ Qi,
    const unsigned short* __restrict__ Krc, const unsigned short* __restrict__ nKic,
    const unsigned short* __restrict__ Vtc, const unsigned short* __restrict__ Vtic,
    const int* __restrict__ cntArr,
    unsigned short* __restrict__ Aaug)
{
    __shared__ short Kr_s[64][LDP], Ki_s[64][LDP], Vr_s[64][LDP], Vi_s[64][LDP];
    __shared__ short P_s[4][32][LDP];

    const int tid = threadIdx.x;
    const int lane = tid & 63, wave = tid >> 6;
    const int lr = lane & 15, lg = lane >> 4;
    const int h = blockIdx.y, b = blockIdx.z;
    const int n0 = blockIdx.x * 128 + wave * 32;
    const size_t qb = ((size_t)(b*HH + h)) * NN * HD;
    const int cnt = cntArr[b];
    const int ct = (cnt + 63) & ~63;

    bf16x8 qr[2][2], qi[2][2];
#pragma unroll
    for (int mf = 0; mf < 2; mf++)
#pragma unroll
        for (int kf = 0; kf < 2; kf++) {
            qr[mf][kf] = *(const bf16x8*)&Qr[qb + (size_t)(n0 + mf*16 + lr) * HD + kf*32 + lg*8];
            qi[mf][kf] = *(const bf16x8*)&Qi[qb + (size_t)(n0 + mf*16 + lr) * HD + kf*32 + lg*8];
        }

    f32x4 o_r[2][4], o_i[2][4];
#pragma unroll
    for (int mf = 0; mf < 2; mf++)
#pragma unroll
        for (int nf = 0; nf < 4; nf++) {
            o_r[mf][nf] = (f32x4){0.f,0.f,0.f,0.f};
            o_i[mf][nf] = (f32x4){0.f,0.f,0.f,0.f};
        }
    float m_run[2][4], l_run[2][4];
#pragma unroll
    for (int mf = 0; mf < 2; mf++)
#pragma unroll
        for (int r = 0; r < 4; r++) { m_run[mf][r] = -3.0e38f; l_run[mf][r] = 0.0f; }

    for (int t0 = 0; t0 < ct; t0 += 64) {
        __syncthreads();
        for (int c = tid; c < 512; c += 256) {
            int row = c >> 3, ch = (c & 7) * 8;
            st8s(&Kr_s[row][ch], *(const bf16x8*)&Krc [qb + (size_t)(t0 + row) * HD + ch]);
            st8s(&Ki_s[row][ch], *(const bf16x8*)&nKic[qb + (size_t)(t0 + row) * HD + ch]);
            st8s(&Vr_s[row][ch], *(const bf16x8*)&Vtc [qb + (size_t)row * NN + t0 + ch]);
            st8s(&Vi_s[row][ch], *(const bf16x8*)&Vtic[qb + (size_t)row * NN + t0 + ch]);
        }
        __syncthreads();

        // ---- scores ----
        f32x4 sacc[2][4];
#pragma unroll
        for (int nf = 0; nf < 4; nf++) {
            bf16x8 k0f = ld8s(&Kr_s[nf*16 + lr][lg*8]);
            bf16x8 k1f = ld8s(&Kr_s[nf*16 + lr][32 + lg*8]);
            bf16x8 i0f = ld8s(&Ki_s[nf*16 + lr][lg*8]);
            bf16x8 i1f = ld8s(&Ki_s[nf*16 + lr][32 + lg*8]);
#pragma unroll
            for (int mf = 0; mf < 2; mf++) {
                f32x4 a = (f32x4){0.f,0.f,0.f,0.f};
                a = MFMA(qr[mf][0], k0f, a);
                a = MFMA(qr[mf][1], k1f, a);
                a = MFMA(qi[mf][0], i0f, a);
                a = MFMA(qi[mf][1], i1f, a);
                sacc[mf][nf] = a;
            }
        }

        // tail masking (only in last tile)
        if (t0 + 64 > cnt) {
#pragma unroll
            for (int nf = 0; nf < 4; nf++) {
                if (t0 + nf*16 + lr >= cnt) {
#pragma unroll
                    for (int mf = 0; mf < 2; mf++)
#pragma unroll
                        for (int r = 0; r < 4; r++) sacc[mf][nf][r] = -1e9f;
                }
            }
        }

        // ---- online softmax (rows = lg*4+r, cols = nf*16+lr) ----
#pragma unroll
        for (int mf = 0; mf < 2; mf++) {
            float fac[4];
#pragma unroll
            for (int r = 0; r < 4; r++) {
                float v = fmaxf(fmaxf(sacc[mf][0][r], sacc[mf][1][r]),
                                fmaxf(sacc[mf][2][r], sacc[mf][3][r]));
                v = fmaxf(v, __shfl_xor(v, 1, 64));
                v = fmaxf(v, __shfl_xor(v, 2, 64));
                v = fmaxf(v, __shfl_xor(v, 4, 64));
                v = fmaxf(v, __shfl_xor(v, 8, 64));
                float mn = fmaxf(m_run[mf][r], v);
                fac[r] = __expf(m_run[mf][r] - mn);
                m_run[mf][r] = mn;
            }
            float psum[4] = {0.f, 0.f, 0.f, 0.f};
#pragma unroll
            for (int nf = 0; nf < 4; nf++)
#pragma unroll
                for (int r = 0; r < 4; r++) {
                    float p = __expf(sacc[mf][nf][r] - m_run[mf][r]);
                    psum[r] += p;
                    P_s[wave][mf*16 + lg*4 + r][nf*16 + lr] = (short)f2bf(p);
                }
#pragma unroll
            for (int r = 0; r < 4; r++) {
                float ps = psum[r];
                ps += __shfl_xor(ps, 1, 64);
                ps += __shfl_xor(ps, 2, 64);
                ps += __shfl_xor(ps, 4, 64);
                ps += __shfl_xor(ps, 8, 64);
                l_run[mf][r] = l_run[mf][r] * fac[r] + ps;
            }
#pragma unroll
            for (int nf = 0; nf < 4; nf++)
#pragma unroll
                for (int r = 0; r < 4; r++) {
                    o_r[mf][nf][r] *= fac[r];
                    o_i[mf][nf][r] *= fac[r];
                }
        }
        __syncthreads();   // P_s visibility

        // ---- PV ----
        bf16x8 pa[2][2];
#pragma unroll
        for (int mf = 0; mf < 2; mf++) {
            pa[mf][0] = ld8s(&P_s[wave][mf*16 + lr][lg*8]);
            pa[mf][1] = ld8s(&P_s[wave][mf*16 + lr][32 + lg*8]);
        }
#pragma unroll
        for (int nf = 0; nf < 4; nf++) {
            bf16x8 v0 = ld8s(&Vr_s[nf*16 + lr][lg*8]);
            bf16x8 v1 = ld8s(&Vr_s[nf*16 + lr][32 + lg*8]);
            bf16x8 w0 = ld8s(&Vi_s[nf*16 + lr][lg*8]);
            bf16x8 w1 = ld8s(&Vi_s[nf*16 + lr][32 + lg*8]);
#pragma unroll
            for (int mf = 0; mf < 2; mf++) {
                o_r[mf][nf] = MFMA(pa[mf][0], v0, o_r[mf][nf]);
                o_r[mf][nf] = MFMA(pa[mf][1], v1, o_r[mf][nf]);
                o_i[mf][nf] = MFMA(pa[mf][0], w0, o_i[mf][nf]);
                o_i[mf][nf] = MFMA(pa[mf][1], w1, o_i[mf][nf]);
            }
        }
    }

#pragma unroll
    for (int mf = 0; mf < 2; mf++) {
        float invl[4];
#pragma unroll
        for (int r = 0; r < 4; r++) invl[r] = 1.0f / l_run[mf][r];
#pragma unroll
        for (int nf = 0; nf < 4; nf++)
#pragma unroll
            for (int r = 0; r < 4; r++) {
                int row = n0 + mf*16 + lg*4 + r;
                int col = h*HD + nf*16 + lr;
                size_t o = ((size_t)(b*NN + row)) * KA + col;
                Aaug[o]        = f2bf(o_r[mf][nf][r] * invl[r]);
                Aaug[o + 1024] = f2bf(o_i[mf][nf][r] * invl[r]);
            }
    }
}

// ---------------------------------------------------------------------------
// Final augmented GEMM + bias + residual: BK=32 3-buffer counted-vmcnt
// pipeline (round-13 passing version, unchanged). grid (32, 16), block 256.
// ---------------------------------------------------------------------------
__global__ __launch_bounds__(256) void final_mfma(
    const unsigned short* __restrict__ Aaug, const unsigned short* __restrict__ Woa,
    const float* __restrict__ bor, const float* __restrict__ boi,
    const float* __restrict__ Zr, const float* __restrict__ Zi,
    float* __restrict__ out)
{
    __shared__ __align__(16) short S[3][2][128][32];

    const int tid = threadIdx.x;
    const int lane = tid & 63, wave = tid >> 6;
    const int lr = lane & 15, lg = lane >> 4;
    const int wrow = (wave >> 1) * 64, wcol = (wave & 1) * 64;
    const int m0 = blockIdx.x * 128, o0 = blockIdx.y * 128;

    const int rsub = lane >> 2;
    const int csrc = (((lane & 3) ^ ((lane >> 3) & 3)) * 8);

    const unsigned short* gp[4];
    int lpo[4];
#pragma unroll
    for (int i = 0; i < 4; i++) {
        const int s = i * 4 + wave;
        if (s < 8) {
            const int row = s * 16 + rsub;
            gp[i] = Aaug + (size_t)(m0 + row) * KA + csrc;
            lpo[i] = s * 1024 + lane * 16;
        } else {
            const int row = (s - 8) * 16 + rsub;
            gp[i] = Woa + (size_t)(o0 + row) * KA + csrc;
            lpo[i] = 8192 + (s - 8) * 1024 + lane * 16;
        }
    }

    f32x4 acc[4][4];
#pragma unroll
    for (int m = 0; m < 4; m++)
#pragma unroll
        for (int n = 0; n < 4; n++) acc[m][n] = (f32x4){0.f,0.f,0.f,0.f};

#pragma unroll
    for (int i = 0; i < 4; i++) { async16((char*)S + lpo[i], gp[i]); gp[i] += 32; }
#pragma unroll
    for (int i = 0; i < 4; i++) { async16((char*)S + 16384 + lpo[i], gp[i]); gp[i] += 32; }

    const int kb = ((lg ^ ((lr >> 1) & 3)) * 8);

    int cur = 0, stg = 2;
    for (int t = 0; t < NT - 1; t++) {
        asm volatile("s_waitcnt vmcnt(4)" ::: "memory");
        __builtin_amdgcn_s_barrier();
        __builtin_amdgcn_sched_barrier(0);

        if (t + 2 < NT) {
            char* nb = (char*)S + stg * 16384;
#pragma unroll
            for (int i = 0; i < 4; i++) { async16(nb + lpo[i], gp[i]); gp[i] += 32; }
        }

        const short (*Sa)[32] = (const short (*)[32])((const char*)S + cur * 16384);
        const short (*Sb)[32] = Sa + 128;
        bf16x8 af[4], bw[4];
#pragma unroll
        for (int m = 0; m < 4; m++) af[m] = *(const bf16x8*)&Sa[wrow + m*16 + lr][kb];
#pragma unroll
        for (int n = 0; n < 4; n++) bw[n] = *(const bf16x8*)&Sb[wcol + n*16 + lr][kb];
#pragma unroll
        for (int m = 0; m < 4; m++)
#pragma unroll
            for (int n = 0; n < 4; n++) acc[m][n] = MFMA(af[m], bw[n], acc[m][n]);

        cur = (cur == 2) ? 0 : cur + 1;
        stg = (stg == 2) ? 0 : stg + 1;
    }
    asm volatile("s_waitcnt vmcnt(0)" ::: "memory");
    __builtin_amdgcn_s_barrier();
    __builtin_amdgcn_sched_barrier(0);
    {
        const short (*Sa)[32] = (const short (*)[32])((const char*)S + cur * 16384);
        const short (*Sb)[32] = Sa + 128;
        bf16x8 af[4], bw[4];
#pragma unroll
        for (int m = 0; m < 4; m++) af[m] = *(const bf16x8*)&Sa[wrow + m*16 + lr][kb];
#pragma unroll
        for (int n = 0; n < 4; n++) bw[n] = *(const bf16x8*)&Sb[wcol + n*16 + lr][kb];
#pragma unroll
        for (int m = 0; m < 4; m++)
#pragma unroll
            for (int n = 0; n < 4; n++) acc[m][n] = MFMA(af[m], bw[n], acc[m][n]);
    }

#pragma unroll
    for (int mi = 0; mi < 4; mi++)
#pragma unroll
        for (int nj = 0; nj < 4; nj++) {
            const int o = o0 + wcol + nj*16 + lr;
            const int half = o >> 10;
            const int oc = o & 1023;
            const float bias = half ? boi[oc] : bor[oc];
            const float* resid = half ? Zi : Zr;
            float* dst = out + (half ? (size_t)MM * DD : 0);
#pragma unroll
            for (int reg = 0; reg < 4; reg++) {
                const int m = m0 + wrow + mi*16 + lg*4 + reg;
                size_t zi = (size_t)m * DD + oc;
                dst[zi] = acc[mi][nj][reg] + bias + resid[zi];
            }
        }
}

// ---------------------------------------------------------------------------
extern "C" void kernel_launch(void* const* d_in, const int* in_sizes, int n_in,
                              void* d_out, int out_size, void* d_ws, size_t ws_size,
                              hipStream_t stream)
{
    const float* Zr  = (const float*)d_in[0];
    const float* Zi  = (const float*)d_in[1];
    const float* wqr = (const float*)d_in[2];
    const float* wqi = (const float*)d_in[3];
    const float* bqr = (const float*)d_in[4];
    const float* bqi = (const float*)d_in[5];
    const float* wkr = (const float*)d_in[6];
    const float* wki = (const float*)d_in[7];
    const float* bkr = (const float*)d_in[8];
    const float* bki = (const float*)d_in[9];
    const float* wvr = (const float*)d_in[10];
    const float* wvi = (const float*)d_in[11];
    const float* bvr = (const float*)d_in[12];
    const float* bvi = (const float*)d_in[13];
    const float* wor = (const float*)d_in[14];
    const float* woi = (const float*)d_in[15];
    const float* bor = (const float*)d_in[16];
    const float* boi = (const float*)d_in[17];
    const int*  mask = (const int*)d_in[18];

    unsigned short* w16 = (unsigned short*)d_ws;
    const size_t ZA = (size_t)MM * KA;      // 8M shorts (16 MB)
    const size_t WA = (size_t)KA * KA;      // 4M shorts (8 MB)
    const size_t HN = (size_t)MM * DD;      // 4M shorts
    unsigned short* Zaug = w16;
    unsigned short* Wqa  = Zaug + ZA;
    unsigned short* Wka  = Wqa + WA;
    unsigned short* Wva  = Wka + WA;
    unsigned short* Woa  = Wva + WA;
    unsigned short* Qr16 = Woa + WA;
    unsigned short* Qi16 = Qr16 + HN;
    unsigned short* Krc16 = Qi16 + HN;
    unsigned short* nKic16 = Krc16 + HN;
    unsigned short* Vtr16 = nKic16 + HN;
    unsigned short* Vti16 = Vtr16 + HN;
    unsigned short* Aaug = Vti16 + HN;
    int* idxArr = (int*)(Aaug + ZA);
    int* cntArr = idxArr + BB * NN;

    cvt_aug<<<12288 + BB, 256, 0, stream>>>(
        Zr, Zi, wqr, wqi, wkr, wki, wvr, wvi, wor, woi,
        Zaug, Wqa, Wka, Wva, Woa, mask, idxArr, cntArr);

    proj_all<<<dim3(96, 16), 256, 0, stream>>>(
        Zaug, Wqa, Wka, Wva,
        bqr, bqi, bkr, bki, bvr, bvi, idxArr, cntArr,
        Qr16, Qi16, Krc16, nKic16, Vtr16, Vti16);

    attn_mfma<<<dim3(NN/128, HH, BB), 256, 0, stream>>>(
        Qr16, Qi16, Krc16, nKic16, Vtr16, Vti16, cntArr, Aaug);

    final_mfma<<<dim3(32, 16), 256, 0, stream>>>(
        Aaug, Woa, bor, boi, Zr, Zi, (float*)d_out);
}